// Round 2
// baseline (2199.581 us; speedup 1.0000x reference)
//
#include <hip/hip_runtime.h>
#include <hip/hip_bf16.h>

#define N_NODES 50000
#define C 128
#define NPAD 50176            // 3136 row-tiles of 16; 392 blocks * 8 tiles
#define NTILES (NPAD / 16)    // 3136
#define GEMM_BLOCKS (NTILES / 8)  // 392

typedef short bf16x8 __attribute__((ext_vector_type(8)));
typedef float f32x4 __attribute__((ext_vector_type(4)));

__device__ __forceinline__ unsigned short f2bf(float f) {
    // round-to-nearest-even fp32 -> bf16
    unsigned int u = __float_as_uint(f);
    unsigned int r = u + 0x7fffu + ((u >> 16) & 1u);
    return (unsigned short)(r >> 16);
}

// ---- degree: deg[dst] += 1  (edges only; computed once, reused both layers)
__global__ void deg_kernel(const int* __restrict__ dst, float* __restrict__ deg, int E) {
    int e = blockIdx.x * 256 + threadIdx.x;
    if (e < E) {
        int d = dst[e];
        if ((unsigned)d < (unsigned)N_NODES) atomicAdd(deg + d, 1.0f);
    }
}

// ---- scatter: agg[dst] += feat[src], 32 lanes per edge, float4 per lane
__global__ __launch_bounds__(256) void scatter_kernel(
    const float* __restrict__ feat, const int* __restrict__ src,
    const int* __restrict__ dst, float* __restrict__ agg, int E) {
    int g = blockIdx.x * 256 + threadIdx.x;
    int e = g >> 5;
    int lane = g & 31;
    if (e >= E) return;
    int s = src[e];
    int d = dst[e];
    if ((unsigned)s >= (unsigned)N_NODES || (unsigned)d >= (unsigned)N_NODES) return;
    const float4 v = *(const float4*)(feat + (size_t)s * C + lane * 4);
    float* a = agg + (size_t)d * C + lane * 4;
    atomicAdd(a + 0, v.x);
    atomicAdd(a + 1, v.y);
    atomicAdd(a + 2, v.z);
    atomicAdd(a + 3, v.w);
}

// ---- prep: F[n] = [bf16(agg[n]/max(deg,1)) | bf16(feat[n])], zero pad rows
__global__ __launch_bounds__(256) void prep_kernel(
    const float* __restrict__ agg, const float* __restrict__ deg,
    const float* __restrict__ feat, unsigned short* __restrict__ F) {
    int g = blockIdx.x * 256 + threadIdx.x;
    int n = g >> 5;
    int ln = g & 31;
    if (n >= NPAD) return;
    unsigned short* row = F + (size_t)n * 256;
    if (n < N_NODES) {
        float d = fmaxf(deg[n], 1.0f);
        float inv = 1.0f / d;
        const float4 a = *(const float4*)(agg + (size_t)n * C + ln * 4);
        const float4 x = *(const float4*)(feat + (size_t)n * C + ln * 4);
        unsigned int m01 = (unsigned)f2bf(a.x * inv) | ((unsigned)f2bf(a.y * inv) << 16);
        unsigned int m23 = (unsigned)f2bf(a.z * inv) | ((unsigned)f2bf(a.w * inv) << 16);
        unsigned int x01 = (unsigned)f2bf(x.x) | ((unsigned)f2bf(x.y) << 16);
        unsigned int x23 = (unsigned)f2bf(x.z) | ((unsigned)f2bf(x.w) << 16);
        *(uint2*)(row + ln * 4) = make_uint2(m01, m23);
        *(uint2*)(row + 128 + ln * 4) = make_uint2(x01, x23);
    } else {
        *(uint2*)(row + ln * 4) = make_uint2(0u, 0u);
        *(uint2*)(row + 128 + ln * 4) = make_uint2(0u, 0u);
    }
}

// ---- weight prep: Wcat[j][k] = (k<128 ? Wl[j][k] : Wr[j][k-128]) as bf16
__global__ void wprep_kernel(const float* __restrict__ Wl, const float* __restrict__ Wr,
                             unsigned short* __restrict__ Wcat) {
    int idx = blockIdx.x * 256 + threadIdx.x;  // 128*256 = 32768
    if (idx >= 128 * 256) return;
    int j = idx >> 8, k = idx & 255;
    float f = (k < 128) ? Wl[j * 128 + k] : Wr[j * 128 + (k - 128)];
    Wcat[idx] = f2bf(f);
}

// ---- GEMM: out[n][j] = sum_k F[n][k]*Wcat[j][k] + bias[j]  (optional relu)
// M = NPAD rows (guard store at N_NODES), N = 128, K = 256
// block = 4 waves; each wave: 2 row-tiles of 16 x full 128 cols (8 col-tiles)
__global__ __launch_bounds__(256) void sage_gemm(
    const unsigned short* __restrict__ F,   // [NPAD,256] bf16
    const unsigned short* __restrict__ Wc,  // [128,256] bf16
    const float* __restrict__ bias,         // [128]
    float* __restrict__ out,                // [N_NODES,128] fp32
    int relu) {
    __shared__ unsigned short wl[128 * 264];  // pitch 264 shorts = 528 B (bank shift 4)
    for (int cidx = threadIdx.x; cidx < 4096; cidx += 256) {
        int row = cidx >> 5, chunk = cidx & 31;
        const uint4 v = *(const uint4*)(Wc + row * 256 + chunk * 8);
        *(uint4*)(&wl[row * 264 + chunk * 8]) = v;
    }
    __syncthreads();

    const int wave = threadIdx.x >> 6;
    const int lane = threadIdx.x & 63;
    const int m = lane & 15;
    const int q = lane >> 4;
    const int tile0 = blockIdx.x * 8 + wave * 2;

    const unsigned short* a0 = F + (size_t)(tile0 * 16 + m) * 256 + q * 8;

    f32x4 acc[2][8];
#pragma unroll
    for (int t = 0; t < 2; ++t)
#pragma unroll
        for (int j = 0; j < 8; ++j) acc[t][j] = (f32x4){0.f, 0.f, 0.f, 0.f};

#pragma unroll
    for (int kt = 0; kt < 8; ++kt) {
        bf16x8 af0 = *(const bf16x8*)(a0 + kt * 32);
        bf16x8 af1 = *(const bf16x8*)(a0 + 16 * 256 + kt * 32);
#pragma unroll
        for (int jt = 0; jt < 8; ++jt) {
            bf16x8 bfrag = *(const bf16x8*)(&wl[(jt * 16 + m) * 264 + kt * 32 + q * 8]);
            acc[0][jt] = __builtin_amdgcn_mfma_f32_16x16x32_bf16(af0, bfrag, acc[0][jt], 0, 0, 0);
            acc[1][jt] = __builtin_amdgcn_mfma_f32_16x16x32_bf16(af1, bfrag, acc[1][jt], 0, 0, 0);
        }
    }

#pragma unroll
    for (int t = 0; t < 2; ++t) {
        int rbase = (tile0 + t) * 16 + q * 4;
#pragma unroll
        for (int r = 0; r < 4; ++r) {
            int row = rbase + r;
            if (row < N_NODES) {
#pragma unroll
                for (int jt = 0; jt < 8; ++jt) {
                    int col = jt * 16 + m;
                    float v = acc[t][jt][r] + bias[col];
                    if (relu) v = fmaxf(v, 0.0f);
                    out[(size_t)row * C + col] = v;
                }
            }
        }
    }
}

extern "C" void kernel_launch(void* const* d_in, const int* in_sizes, int n_in,
                              void* d_out, int out_size, void* d_ws, size_t ws_size,
                              hipStream_t stream) {
    const float* x = (const float*)d_in[0];
    const int* edge = (const int*)d_in[1];   // int64 in reference -> int32 in harness
    const float* Wl1 = (const float*)d_in[2];
    const float* bl1 = (const float*)d_in[3];
    const float* Wr1 = (const float*)d_in[4];
    const float* Wl2 = (const float*)d_in[5];
    const float* bl2 = (const float*)d_in[6];
    const float* Wr2 = (const float*)d_in[7];
    float* out = (float*)d_out;

    const int E = in_sizes[1] / 2;
    const int* src = edge;
    const int* dst = edge + E;

    // workspace layout
    char* ws = (char*)d_ws;
    size_t off = 0;
    float* agg = (float*)(ws + off);          off += (size_t)N_NODES * C * 4;       // 25,600,000
    float* deg = (float*)(ws + off);          off += ((size_t)N_NODES * 4 + 511) & ~511ull;
    unsigned short* F = (unsigned short*)(ws + off); off += (size_t)NPAD * 256 * 2; // 25,690,112
    unsigned short* Wc1 = (unsigned short*)(ws + off); off += 128 * 256 * 2;
    unsigned short* Wc2 = (unsigned short*)(ws + off); off += 128 * 256 * 2;
    float* h = (float*)(ws + off);            off += (size_t)N_NODES * C * 4;
    (void)ws_size;

    const int scatterBlocks = (E * 32 + 255) / 256;
    const int degBlocks = (E + 255) / 256;
    const int prepBlocks = (NPAD * 32) / 256;

    // once-per-call setup
    hipMemsetAsync(deg, 0, (size_t)N_NODES * 4, stream);
    hipMemsetAsync(agg, 0, (size_t)N_NODES * C * 4, stream);
    deg_kernel<<<degBlocks, 256, 0, stream>>>(dst, deg, E);
    wprep_kernel<<<128, 256, 0, stream>>>(Wl1, Wr1, Wc1);
    wprep_kernel<<<128, 256, 0, stream>>>(Wl2, Wr2, Wc2);

    // layer 1
    scatter_kernel<<<scatterBlocks, 256, 0, stream>>>(x, src, dst, agg, E);
    prep_kernel<<<prepBlocks, 256, 0, stream>>>(agg, deg, x, F);
    sage_gemm<<<GEMM_BLOCKS, 256, 0, stream>>>(F, Wc1, bl1, h, 1);

    // layer 2
    hipMemsetAsync(agg, 0, (size_t)N_NODES * C * 4, stream);
    scatter_kernel<<<scatterBlocks, 256, 0, stream>>>(h, src, dst, agg, E);
    prep_kernel<<<prepBlocks, 256, 0, stream>>>(agg, deg, h, F);
    sage_gemm<<<GEMM_BLOCKS, 256, 0, stream>>>(F, Wc2, bl2, out, 0);
}

// Round 3
// 367.229 us; speedup vs baseline: 5.9897x; 5.9897x over previous
//
#include <hip/hip_runtime.h>
#include <hip/hip_bf16.h>

#define N_NODES 50000
#define C 128
#define NPAD 50176            // 3136 row-tiles of 16; 392 blocks * 8 tiles
#define NTILES (NPAD / 16)    // 3136
#define GEMM_BLOCKS (NTILES / 8)  // 392
#define SCAN_THREADS 1024
#define SCAN_PER 49           // 1024*49 = 50176 >= 50000

typedef short bf16x8 __attribute__((ext_vector_type(8)));
typedef float f32x4 __attribute__((ext_vector_type(4)));

__device__ __forceinline__ unsigned short f2bf(float f) {
    // round-to-nearest-even fp32 -> bf16
    unsigned int u = __float_as_uint(f);
    unsigned int r = u + 0x7fffu + ((u >> 16) & 1u);
    return (unsigned short)(r >> 16);
}

// ---- degree histogram (int), computed once, reused both layers
__global__ void deg_kernel(const int* __restrict__ dst, int* __restrict__ deg, int E) {
    int e = blockIdx.x * 256 + threadIdx.x;
    if (e < E) {
        int d = dst[e];
        if ((unsigned)d < (unsigned)N_NODES) atomicAdd(deg + d, 1);
    }
}

// ---- exclusive prefix scan of deg -> row_ptr[0..N_NODES], single block
__global__ __launch_bounds__(SCAN_THREADS) void scan_kernel(
    const int* __restrict__ deg, int* __restrict__ row_ptr) {
    __shared__ int sums[SCAN_THREADS];
    const int t = threadIdx.x;
    const int base = t * SCAN_PER;
    int local[SCAN_PER];
    int s = 0;
#pragma unroll
    for (int i = 0; i < SCAN_PER; ++i) {
        int idx = base + i;
        int v = (idx < N_NODES) ? deg[idx] : 0;
        local[i] = s;
        s += v;
    }
    sums[t] = s;
    __syncthreads();
    // Hillis-Steele inclusive scan over 1024 partials
    for (int off = 1; off < SCAN_THREADS; off <<= 1) {
        int tmp = (t >= off) ? sums[t - off] : 0;
        __syncthreads();
        sums[t] += tmp;
        __syncthreads();
    }
    int excl = (t == 0) ? 0 : sums[t - 1];
#pragma unroll
    for (int i = 0; i < SCAN_PER; ++i) {
        int idx = base + i;
        if (idx < N_NODES) row_ptr[idx] = excl + local[i];
    }
    if (t == SCAN_THREADS - 1) row_ptr[N_NODES] = excl + s;
}

// ---- fill CSR: csr_src[row_ptr[d] + cursor[d]++] = s
__global__ void fill_kernel(const int* __restrict__ src, const int* __restrict__ dst,
                            const int* __restrict__ row_ptr, int* __restrict__ cursor,
                            int* __restrict__ csr_src, int E) {
    int e = blockIdx.x * 256 + threadIdx.x;
    if (e < E) {
        int d = dst[e];
        int s = src[e];
        if ((unsigned)d < (unsigned)N_NODES && (unsigned)s < (unsigned)N_NODES) {
            int pos = row_ptr[d] + atomicAdd(cursor + d, 1);
            csr_src[pos] = s;
        }
    }
}

// ---- fused gather + mean + bf16 prep: one wave per node
// F[n] = [bf16(mean_{s in N(n)} feat[s]) | bf16(feat[n])], pad rows zeroed
__global__ __launch_bounds__(256) void gather_kernel(
    const float* __restrict__ feat, const int* __restrict__ row_ptr,
    const int* __restrict__ csr_src, unsigned short* __restrict__ F) {
    int w = (blockIdx.x * 256 + threadIdx.x) >> 6;   // node id (one wave each)
    int lane = threadIdx.x & 63;
    if (w >= NPAD) return;
    unsigned short* row = F + (size_t)w * 256;
    if (w >= N_NODES) {
        *(unsigned int*)(row + lane * 2) = 0u;
        *(unsigned int*)(row + 128 + lane * 2) = 0u;
        return;
    }
    const int beg = row_ptr[w], end = row_ptr[w + 1];
    float ax = 0.f, ay = 0.f;
    const float* fp = feat + lane * 2;
    for (int i = beg; i < end; ++i) {
        int s = csr_src[i];
        const float2 v = *(const float2*)(fp + (size_t)s * C);
        ax += v.x;
        ay += v.y;
    }
    const float inv = 1.0f / fmaxf((float)(end - beg), 1.0f);
    unsigned int mpack = (unsigned)f2bf(ax * inv) | ((unsigned)f2bf(ay * inv) << 16);
    const float2 xv = *(const float2*)(feat + (size_t)w * C + lane * 2);
    unsigned int xpack = (unsigned)f2bf(xv.x) | ((unsigned)f2bf(xv.y) << 16);
    *(unsigned int*)(row + lane * 2) = mpack;
    *(unsigned int*)(row + 128 + lane * 2) = xpack;
}

// ---- weight prep: Wcat[j][k] = (k<128 ? Wl[j][k] : Wr[j][k-128]) as bf16
__global__ void wprep_kernel(const float* __restrict__ Wl, const float* __restrict__ Wr,
                             unsigned short* __restrict__ Wcat) {
    int idx = blockIdx.x * 256 + threadIdx.x;  // 128*256 = 32768
    if (idx >= 128 * 256) return;
    int j = idx >> 8, k = idx & 255;
    float f = (k < 128) ? Wl[j * 128 + k] : Wr[j * 128 + (k - 128)];
    Wcat[idx] = f2bf(f);
}

// ---- GEMM: out[n][j] = sum_k F[n][k]*Wcat[j][k] + bias[j]  (optional relu)
// M = NPAD rows (guard store at N_NODES), N = 128, K = 256
__global__ __launch_bounds__(256) void sage_gemm(
    const unsigned short* __restrict__ F,   // [NPAD,256] bf16
    const unsigned short* __restrict__ Wc,  // [128,256] bf16
    const float* __restrict__ bias,         // [128]
    float* __restrict__ out,                // [N_NODES,128] fp32
    int relu) {
    __shared__ unsigned short wl[128 * 264];  // pitch 264 shorts = 528 B (bank shift 4)
    for (int cidx = threadIdx.x; cidx < 4096; cidx += 256) {
        int row = cidx >> 5, chunk = cidx & 31;
        const uint4 v = *(const uint4*)(Wc + row * 256 + chunk * 8);
        *(uint4*)(&wl[row * 264 + chunk * 8]) = v;
    }
    __syncthreads();

    const int wave = threadIdx.x >> 6;
    const int lane = threadIdx.x & 63;
    const int m = lane & 15;
    const int q = lane >> 4;
    const int tile0 = blockIdx.x * 8 + wave * 2;

    const unsigned short* a0 = F + (size_t)(tile0 * 16 + m) * 256 + q * 8;

    f32x4 acc[2][8];
#pragma unroll
    for (int t = 0; t < 2; ++t)
#pragma unroll
        for (int j = 0; j < 8; ++j) acc[t][j] = (f32x4){0.f, 0.f, 0.f, 0.f};

#pragma unroll
    for (int kt = 0; kt < 8; ++kt) {
        bf16x8 af0 = *(const bf16x8*)(a0 + kt * 32);
        bf16x8 af1 = *(const bf16x8*)(a0 + 16 * 256 + kt * 32);
#pragma unroll
        for (int jt = 0; jt < 8; ++jt) {
            bf16x8 bfrag = *(const bf16x8*)(&wl[(jt * 16 + m) * 264 + kt * 32 + q * 8]);
            acc[0][jt] = __builtin_amdgcn_mfma_f32_16x16x32_bf16(af0, bfrag, acc[0][jt], 0, 0, 0);
            acc[1][jt] = __builtin_amdgcn_mfma_f32_16x16x32_bf16(af1, bfrag, acc[1][jt], 0, 0, 0);
        }
    }

#pragma unroll
    for (int t = 0; t < 2; ++t) {
        int rbase = (tile0 + t) * 16 + q * 4;
#pragma unroll
        for (int r = 0; r < 4; ++r) {
            int row = rbase + r;
            if (row < N_NODES) {
#pragma unroll
                for (int jt = 0; jt < 8; ++jt) {
                    int col = jt * 16 + m;
                    float v = acc[t][jt][r] + bias[col];
                    if (relu) v = fmaxf(v, 0.0f);
                    out[(size_t)row * C + col] = v;
                }
            }
        }
    }
}

extern "C" void kernel_launch(void* const* d_in, const int* in_sizes, int n_in,
                              void* d_out, int out_size, void* d_ws, size_t ws_size,
                              hipStream_t stream) {
    const float* x = (const float*)d_in[0];
    const int* edge = (const int*)d_in[1];   // int64 in reference -> int32 in harness
    const float* Wl1 = (const float*)d_in[2];
    const float* bl1 = (const float*)d_in[3];
    const float* Wr1 = (const float*)d_in[4];
    const float* Wl2 = (const float*)d_in[5];
    const float* bl2 = (const float*)d_in[6];
    const float* Wr2 = (const float*)d_in[7];
    float* out = (float*)d_out;

    const int E = in_sizes[1] / 2;
    const int* src = edge;
    const int* dst = edge + E;

    // workspace layout
    char* ws = (char*)d_ws;
    size_t off = 0;
    int* deg = (int*)(ws + off);              off += ((size_t)N_NODES * 4 + 511) & ~511ull;
    int* row_ptr = (int*)(ws + off);          off += ((size_t)(N_NODES + 1) * 4 + 511) & ~511ull;
    int* cursor = (int*)(ws + off);           off += ((size_t)N_NODES * 4 + 511) & ~511ull;
    int* csr_src = (int*)(ws + off);          off += ((size_t)E * 4 + 511) & ~511ull;
    unsigned short* F = (unsigned short*)(ws + off); off += (size_t)NPAD * 256 * 2; // 25.7 MB
    unsigned short* Wc1 = (unsigned short*)(ws + off); off += 128 * 256 * 2;
    unsigned short* Wc2 = (unsigned short*)(ws + off); off += 128 * 256 * 2;
    float* h = (float*)(ws + off);            off += (size_t)N_NODES * C * 4;       // 25.6 MB
    (void)ws_size;

    const int edgeBlocks = (E + 255) / 256;
    const int gatherBlocks = (NPAD * 64) / 256;  // one wave per node

    // CSR build (once; reused by both layers)
    hipMemsetAsync(deg, 0, (size_t)N_NODES * 4, stream);
    hipMemsetAsync(cursor, 0, (size_t)N_NODES * 4, stream);
    deg_kernel<<<edgeBlocks, 256, 0, stream>>>(dst, deg, E);
    scan_kernel<<<1, SCAN_THREADS, 0, stream>>>(deg, row_ptr);
    fill_kernel<<<edgeBlocks, 256, 0, stream>>>(src, dst, row_ptr, cursor, csr_src, E);
    wprep_kernel<<<128, 256, 0, stream>>>(Wl1, Wr1, Wc1);
    wprep_kernel<<<128, 256, 0, stream>>>(Wl2, Wr2, Wc2);

    // layer 1
    gather_kernel<<<gatherBlocks, 256, 0, stream>>>(x, row_ptr, csr_src, F);
    sage_gemm<<<GEMM_BLOCKS, 256, 0, stream>>>(F, Wc1, bl1, h, 1);

    // layer 2
    gather_kernel<<<gatherBlocks, 256, 0, stream>>>(h, row_ptr, csr_src, F);
    sage_gemm<<<GEMM_BLOCKS, 256, 0, stream>>>(F, Wc2, bl2, out, 0);
}

// Round 4
// 328.978 us; speedup vs baseline: 6.6861x; 1.1163x over previous
//
#include <hip/hip_runtime.h>
#include <hip/hip_bf16.h>

#define N_NODES 50000
#define C 128
#define NPAD 50176            // 3136 row-tiles of 16; 392 blocks * 8 tiles
#define NTILES (NPAD / 16)
#define GEMM_BLOCKS (NTILES / 8)  // 392
#define SCAN_THREADS 1024
#define SCAN_PER 49           // 1024*49 = 50176 >= 50000

typedef short bf16x8 __attribute__((ext_vector_type(8)));
typedef float f32x4 __attribute__((ext_vector_type(4)));

__device__ __forceinline__ unsigned short f2bf(float f) {
    unsigned int u = __float_as_uint(f);
    unsigned int r = u + 0x7fffu + ((u >> 16) & 1u);
    return (unsigned short)(r >> 16);
}

__device__ __forceinline__ float bf2f(unsigned short b) {
    return __uint_as_float(((unsigned int)b) << 16);
}

// ---- x -> bf16 copy (once)
__global__ __launch_bounds__(256) void xprep_kernel(const float* __restrict__ x,
                                                    unsigned short* __restrict__ Xb) {
    int t = blockIdx.x * 256 + threadIdx.x;          // 800000 threads, 8 elems each
    if (t >= N_NODES * C / 8) return;
    const float4 a = *(const float4*)(x + (size_t)t * 8);
    const float4 b = *(const float4*)(x + (size_t)t * 8 + 4);
    unsigned short o[8] = {f2bf(a.x), f2bf(a.y), f2bf(a.z), f2bf(a.w),
                           f2bf(b.x), f2bf(b.y), f2bf(b.z), f2bf(b.w)};
    *(uint4*)(Xb + (size_t)t * 8) = *(const uint4*)o;
}

// ---- degree histogram (int), once
__global__ void deg_kernel(const int* __restrict__ dst, int* __restrict__ deg, int E) {
    int e = blockIdx.x * 256 + threadIdx.x;
    if (e < E) {
        int d = dst[e];
        if ((unsigned)d < (unsigned)N_NODES) atomicAdd(deg + d, 1);
    }
}

// ---- exclusive prefix scan of deg -> row_ptr[0..N_NODES], single block
__global__ __launch_bounds__(SCAN_THREADS) void scan_kernel(
    const int* __restrict__ deg, int* __restrict__ row_ptr) {
    __shared__ int sums[SCAN_THREADS];
    const int t = threadIdx.x;
    const int base = t * SCAN_PER;
    int local[SCAN_PER];
    int s = 0;
#pragma unroll
    for (int i = 0; i < SCAN_PER; ++i) {
        int idx = base + i;
        int v = (idx < N_NODES) ? deg[idx] : 0;
        local[i] = s;
        s += v;
    }
    sums[t] = s;
    __syncthreads();
    for (int off = 1; off < SCAN_THREADS; off <<= 1) {
        int tmp = (t >= off) ? sums[t - off] : 0;
        __syncthreads();
        sums[t] += tmp;
        __syncthreads();
    }
    int excl = (t == 0) ? 0 : sums[t - 1];
#pragma unroll
    for (int i = 0; i < SCAN_PER; ++i) {
        int idx = base + i;
        if (idx < N_NODES) row_ptr[idx] = excl + local[i];
    }
    if (t == SCAN_THREADS - 1) row_ptr[N_NODES] = excl + s;
}

// ---- fill CSR
__global__ void fill_kernel(const int* __restrict__ src, const int* __restrict__ dst,
                            const int* __restrict__ row_ptr, int* __restrict__ cursor,
                            int* __restrict__ csr_src, int E) {
    int e = blockIdx.x * 256 + threadIdx.x;
    if (e < E) {
        int d = dst[e];
        int s = src[e];
        if ((unsigned)d < (unsigned)N_NODES && (unsigned)s < (unsigned)N_NODES) {
            int pos = row_ptr[d] + atomicAdd(cursor + d, 1);
            csr_src[pos] = s;
        }
    }
}

// ---- gather mean from bf16 features: one wave per node, 2 bf16 per lane
// Fm[n] = bf16(mean_{s in N(n)} feat[s]); pad rows untouched (never stored)
__global__ __launch_bounds__(256) void gather_kernel(
    const unsigned short* __restrict__ feat,  // [*, 128] bf16
    const int* __restrict__ row_ptr, const int* __restrict__ csr_src,
    unsigned short* __restrict__ Fm) {
    int w = (blockIdx.x * 256 + threadIdx.x) >> 6;   // node id (one wave each)
    int lane = threadIdx.x & 63;
    if (w >= N_NODES) return;
    const int beg = row_ptr[w], end = row_ptr[w + 1];
    float ax = 0.f, ay = 0.f;
    const unsigned short* fp = feat + lane * 2;
    int i = beg;
    for (; i + 1 < end; i += 2) {
        int s0 = csr_src[i];
        int s1 = csr_src[i + 1];
        unsigned int u0 = *(const unsigned int*)(fp + (size_t)s0 * C);
        unsigned int u1 = *(const unsigned int*)(fp + (size_t)s1 * C);
        ax += bf2f((unsigned short)u0) + bf2f((unsigned short)u1);
        ay += bf2f((unsigned short)(u0 >> 16)) + bf2f((unsigned short)(u1 >> 16));
    }
    if (i < end) {
        int s0 = csr_src[i];
        unsigned int u0 = *(const unsigned int*)(fp + (size_t)s0 * C);
        ax += bf2f((unsigned short)u0);
        ay += bf2f((unsigned short)(u0 >> 16));
    }
    const float inv = 1.0f / fmaxf((float)(end - beg), 1.0f);
    unsigned int mpack = (unsigned)f2bf(ax * inv) | ((unsigned)f2bf(ay * inv) << 16);
    *(unsigned int*)(Fm + (size_t)w * C + lane * 2) = mpack;
}

// ---- weight prep, both layers in one launch:
// Wcat[j][k] = bf16(k<128 ? Wl[j][k] : Wr[j][k-128])
__global__ void wprep_kernel(const float* __restrict__ Wl1, const float* __restrict__ Wr1,
                             const float* __restrict__ Wl2, const float* __restrict__ Wr2,
                             unsigned short* __restrict__ Wc1, unsigned short* __restrict__ Wc2) {
    int idx = blockIdx.x * 256 + threadIdx.x;  // 2*128*256 = 65536
    if (idx >= 2 * 128 * 256) return;
    int layer = idx >> 15;
    int r = idx & 32767;
    int j = r >> 8, k = r & 255;
    const float* Wl = layer ? Wl2 : Wl1;
    const float* Wr = layer ? Wr2 : Wr1;
    unsigned short* Wc = layer ? Wc2 : Wc1;
    float f = (k < 128) ? Wl[j * 128 + k] : Wr[j * 128 + (k - 128)];
    Wc[r] = f2bf(f);
}

// ---- GEMM: out[n][j] = sum_k A[n][k]*Wc[j][k] + bias[j]
// A = [Fm | Self] (two [*,128] bf16 matrices), M = NPAD, N = 128, K = 256
// obf16: out is bf16[*,128] (with relu), else fp32 (no relu)
__global__ __launch_bounds__(256) void sage_gemm(
    const unsigned short* __restrict__ Fm,    // [NPAD,128] bf16 (mean)
    const unsigned short* __restrict__ Self,  // [NPAD,128] bf16 (self feats)
    const unsigned short* __restrict__ Wc,    // [128,256] bf16
    const float* __restrict__ bias,           // [128]
    void* __restrict__ outv, int relu, int obf16) {
    __shared__ unsigned short wl[128 * 264];  // pitch 264 shorts (bank shift 4)
    for (int cidx = threadIdx.x; cidx < 4096; cidx += 256) {
        int row = cidx >> 5, chunk = cidx & 31;
        const uint4 v = *(const uint4*)(Wc + row * 256 + chunk * 8);
        *(uint4*)(&wl[row * 264 + chunk * 8]) = v;
    }
    __syncthreads();

    const int wave = threadIdx.x >> 6;
    const int lane = threadIdx.x & 63;
    const int m = lane & 15;
    const int q = lane >> 4;
    const int tile0 = blockIdx.x * 8 + wave * 2;

    const size_t rowoff = (size_t)(tile0 * 16 + m) * C + q * 8;
    const unsigned short* am = Fm + rowoff;
    const unsigned short* as = Self + rowoff;

    f32x4 acc[2][8];
#pragma unroll
    for (int t = 0; t < 2; ++t)
#pragma unroll
        for (int j = 0; j < 8; ++j) acc[t][j] = (f32x4){0.f, 0.f, 0.f, 0.f};

#pragma unroll
    for (int kt = 0; kt < 8; ++kt) {
        const unsigned short* A = (kt < 4) ? am : as;
        const int ko = (kt & 3) * 32;
        bf16x8 af0 = *(const bf16x8*)(A + ko);
        bf16x8 af1 = *(const bf16x8*)(A + 16 * C + ko);
#pragma unroll
        for (int jt = 0; jt < 8; ++jt) {
            bf16x8 bfrag = *(const bf16x8*)(&wl[(jt * 16 + m) * 264 + kt * 32 + q * 8]);
            acc[0][jt] = __builtin_amdgcn_mfma_f32_16x16x32_bf16(af0, bfrag, acc[0][jt], 0, 0, 0);
            acc[1][jt] = __builtin_amdgcn_mfma_f32_16x16x32_bf16(af1, bfrag, acc[1][jt], 0, 0, 0);
        }
    }

#pragma unroll
    for (int t = 0; t < 2; ++t) {
        int rbase = (tile0 + t) * 16 + q * 4;
#pragma unroll
        for (int r = 0; r < 4; ++r) {
            int row = rbase + r;
            if (row < N_NODES) {
#pragma unroll
                for (int jt = 0; jt < 8; ++jt) {
                    int col = jt * 16 + m;
                    float v = acc[t][jt][r] + bias[col];
                    if (relu) v = fmaxf(v, 0.0f);
                    if (obf16)
                        ((unsigned short*)outv)[(size_t)row * C + col] = f2bf(v);
                    else
                        ((float*)outv)[(size_t)row * C + col] = v;
                }
            }
        }
    }
}

extern "C" void kernel_launch(void* const* d_in, const int* in_sizes, int n_in,
                              void* d_out, int out_size, void* d_ws, size_t ws_size,
                              hipStream_t stream) {
    const float* x = (const float*)d_in[0];
    const int* edge = (const int*)d_in[1];   // int64 in reference -> int32 in harness
    const float* Wl1 = (const float*)d_in[2];
    const float* bl1 = (const float*)d_in[3];
    const float* Wr1 = (const float*)d_in[4];
    const float* Wl2 = (const float*)d_in[5];
    const float* bl2 = (const float*)d_in[6];
    const float* Wr2 = (const float*)d_in[7];
    float* out = (float*)d_out;

    const int E = in_sizes[1] / 2;
    const int* src = edge;
    const int* dst = edge + E;

    // workspace layout
    char* ws = (char*)d_ws;
    size_t off = 0;
    int* deg = (int*)(ws + off);              off += ((size_t)N_NODES * 4 + 511) & ~511ull;
    int* row_ptr = (int*)(ws + off);          off += ((size_t)(N_NODES + 1) * 4 + 511) & ~511ull;
    int* cursor = (int*)(ws + off);           off += ((size_t)N_NODES * 4 + 511) & ~511ull;
    int* csr_src = (int*)(ws + off);          off += ((size_t)E * 4 + 511) & ~511ull;
    unsigned short* Xb = (unsigned short*)(ws + off); off += (size_t)NPAD * C * 2;  // 12.8 MB
    unsigned short* Fm = (unsigned short*)(ws + off); off += (size_t)NPAD * C * 2;  // 12.8 MB
    unsigned short* h  = (unsigned short*)(ws + off); off += (size_t)NPAD * C * 2;  // 12.8 MB
    unsigned short* Wc1 = (unsigned short*)(ws + off); off += 128 * 256 * 2;
    unsigned short* Wc2 = (unsigned short*)(ws + off); off += 128 * 256 * 2;
    (void)ws_size;

    const int edgeBlocks = (E + 255) / 256;
    const int gatherBlocks = (NPAD * 64) / 256;   // one wave per node
    const int xprepBlocks = (N_NODES * C / 8 + 255) / 256;

    // CSR build + weight/feature conversion (once)
    hipMemsetAsync(deg, 0, (size_t)N_NODES * 4, stream);
    hipMemsetAsync(cursor, 0, (size_t)N_NODES * 4, stream);
    deg_kernel<<<edgeBlocks, 256, 0, stream>>>(dst, deg, E);
    scan_kernel<<<1, SCAN_THREADS, 0, stream>>>(deg, row_ptr);
    fill_kernel<<<edgeBlocks, 256, 0, stream>>>(src, dst, row_ptr, cursor, csr_src, E);
    xprep_kernel<<<xprepBlocks, 256, 0, stream>>>(x, Xb);
    wprep_kernel<<<256, 256, 0, stream>>>(Wl1, Wr1, Wl2, Wr2, Wc1, Wc2);

    // layer 1
    gather_kernel<<<gatherBlocks, 256, 0, stream>>>(Xb, row_ptr, csr_src, Fm);
    sage_gemm<<<GEMM_BLOCKS, 256, 0, stream>>>(Fm, Xb, Wc1, bl1, h, 1, 1);

    // layer 2
    gather_kernel<<<gatherBlocks, 256, 0, stream>>>(h, row_ptr, csr_src, Fm);
    sage_gemm<<<GEMM_BLOCKS, 256, 0, stream>>>(Fm, h, Wc2, bl2, out, 0, 0);
}

// Round 5
// 282.456 us; speedup vs baseline: 7.7873x; 1.1647x over previous
//
#include <hip/hip_runtime.h>
#include <hip/hip_bf16.h>

#define N_NODES 50000
#define C 128
#define NPAD 50176            // 3136 row-tiles of 16; 392 blocks * 8 tiles
#define NTILES (NPAD / 16)
#define GEMM_BLOCKS (NTILES / 8)  // 392
#define SCAN1_BLOCKS (NPAD / 256) // 196

typedef short bf16x8 __attribute__((ext_vector_type(8)));
typedef float f32x4 __attribute__((ext_vector_type(4)));

__device__ __forceinline__ unsigned short f2bf(float f) {
    unsigned int u = __float_as_uint(f);
    unsigned int r = u + 0x7fffu + ((u >> 16) & 1u);
    return (unsigned short)(r >> 16);
}

__device__ __forceinline__ float bf2f(unsigned short b) {
    return __uint_as_float(((unsigned int)b) << 16);
}

// ---- x -> bf16 copy (once)
__global__ __launch_bounds__(256) void xprep_kernel(const float* __restrict__ x,
                                                    unsigned short* __restrict__ Xb) {
    int t = blockIdx.x * 256 + threadIdx.x;
    if (t >= N_NODES * C / 8) return;
    const float4 a = *(const float4*)(x + (size_t)t * 8);
    const float4 b = *(const float4*)(x + (size_t)t * 8 + 4);
    unsigned short o[8] = {f2bf(a.x), f2bf(a.y), f2bf(a.z), f2bf(a.w),
                           f2bf(b.x), f2bf(b.y), f2bf(b.z), f2bf(b.w)};
    *(uint4*)(Xb + (size_t)t * 8) = *(const uint4*)o;
}

// ---- degree histogram (int), once
__global__ void deg_kernel(const int* __restrict__ dst, int* __restrict__ deg, int E) {
    int e = blockIdx.x * 256 + threadIdx.x;
    if (e < E) {
        int d = dst[e];
        if ((unsigned)d < (unsigned)N_NODES) atomicAdd(deg + d, 1);
    }
}

// ---- hierarchical exclusive scan: scan1 (per-block) -> scan2 (block sums) -> scan3 (add)
__global__ __launch_bounds__(256) void scan1_kernel(const int* __restrict__ deg,
                                                    int* __restrict__ scanbuf,
                                                    int* __restrict__ blocksum) {
    int i = blockIdx.x * 256 + threadIdx.x;
    int v = (i < N_NODES) ? deg[i] : 0;
    int lane = threadIdx.x & 63;
    int wv = threadIdx.x >> 6;
    int s = v;
#pragma unroll
    for (int off = 1; off < 64; off <<= 1) {
        int t = __shfl_up(s, off, 64);
        if (lane >= off) s += t;
    }
    __shared__ int wsum[4];
    if (lane == 63) wsum[wv] = s;
    __syncthreads();
    int woff = 0;
#pragma unroll
    for (int k = 0; k < 4; ++k) woff += (k < wv) ? wsum[k] : 0;
    scanbuf[i] = s + woff - v;                       // block-local exclusive
    if (threadIdx.x == 255) blocksum[blockIdx.x] = s + woff;  // block total
}

__global__ __launch_bounds__(256) void scan2_kernel(const int* __restrict__ blocksum,
                                                    int* __restrict__ blockoff) {
    int t = threadIdx.x;
    int v = (t < SCAN1_BLOCKS) ? blocksum[t] : 0;
    int lane = t & 63, wv = t >> 6;
    int s = v;
#pragma unroll
    for (int off = 1; off < 64; off <<= 1) {
        int tmp = __shfl_up(s, off, 64);
        if (lane >= off) s += tmp;
    }
    __shared__ int wsum[4];
    if (lane == 63) wsum[wv] = s;
    __syncthreads();
    int woff = 0;
#pragma unroll
    for (int k = 0; k < 4; ++k) woff += (k < wv) ? wsum[k] : 0;
    if (t < SCAN1_BLOCKS) blockoff[t] = s + woff - v;   // exclusive block offsets
}

__global__ __launch_bounds__(256) void scan3_kernel(const int* __restrict__ scanbuf,
                                                    const int* __restrict__ blockoff,
                                                    int* __restrict__ row_ptr) {
    int i = blockIdx.x * 256 + threadIdx.x;   // covers 0..NPAD-1 incl. index 50000
    row_ptr[i] = scanbuf[i] + blockoff[blockIdx.x];
}

// ---- fill CSR
__global__ void fill_kernel(const int* __restrict__ src, const int* __restrict__ dst,
                            const int* __restrict__ row_ptr, int* __restrict__ cursor,
                            int* __restrict__ csr_src, int E) {
    int e = blockIdx.x * 256 + threadIdx.x;
    if (e < E) {
        int d = dst[e];
        int s = src[e];
        if ((unsigned)d < (unsigned)N_NODES && (unsigned)s < (unsigned)N_NODES) {
            int pos = row_ptr[d] + atomicAdd(cursor + d, 1);
            csr_src[pos] = s;
        }
    }
}

// ---- gather mean from bf16 features: one wave per node, 2 bf16 per lane
__global__ __launch_bounds__(256) void gather_kernel(
    const unsigned short* __restrict__ feat,  // [*, 128] bf16
    const int* __restrict__ row_ptr, const int* __restrict__ csr_src,
    unsigned short* __restrict__ Fm) {
    int w = (blockIdx.x * 256 + threadIdx.x) >> 6;   // node id (one wave each)
    int lane = threadIdx.x & 63;
    if (w >= N_NODES) return;
    const int beg = row_ptr[w], end = row_ptr[w + 1];
    float ax = 0.f, ay = 0.f;
    const unsigned short* fp = feat + lane * 2;
    int i = beg;
    for (; i + 1 < end; i += 2) {
        int s0 = csr_src[i];
        int s1 = csr_src[i + 1];
        unsigned int u0 = *(const unsigned int*)(fp + (size_t)s0 * C);
        unsigned int u1 = *(const unsigned int*)(fp + (size_t)s1 * C);
        ax += bf2f((unsigned short)u0) + bf2f((unsigned short)u1);
        ay += bf2f((unsigned short)(u0 >> 16)) + bf2f((unsigned short)(u1 >> 16));
    }
    if (i < end) {
        int s0 = csr_src[i];
        unsigned int u0 = *(const unsigned int*)(fp + (size_t)s0 * C);
        ax += bf2f((unsigned short)u0);
        ay += bf2f((unsigned short)(u0 >> 16));
    }
    const float inv = 1.0f / fmaxf((float)(end - beg), 1.0f);
    unsigned int mpack = (unsigned)f2bf(ax * inv) | ((unsigned)f2bf(ay * inv) << 16);
    *(unsigned int*)(Fm + (size_t)w * C + lane * 2) = mpack;
}

// ---- weight prep, both layers in one launch
__global__ void wprep_kernel(const float* __restrict__ Wl1, const float* __restrict__ Wr1,
                             const float* __restrict__ Wl2, const float* __restrict__ Wr2,
                             unsigned short* __restrict__ Wc1, unsigned short* __restrict__ Wc2) {
    int idx = blockIdx.x * 256 + threadIdx.x;  // 2*128*256 = 65536
    if (idx >= 2 * 128 * 256) return;
    int layer = idx >> 15;
    int r = idx & 32767;
    int j = r >> 8, k = r & 255;
    const float* Wl = layer ? Wl2 : Wl1;
    const float* Wr = layer ? Wr2 : Wr1;
    unsigned short* Wc = layer ? Wc2 : Wc1;
    float f = (k < 128) ? Wl[j * 128 + k] : Wr[j * 128 + (k - 128)];
    Wc[r] = f2bf(f);
}

// ---- GEMM: out[n][j] = sum_k A[n][k]*Wc[j][k] + bias[j]
// A = [Fm | Self] (two [*,128] bf16 matrices), M = NPAD, N = 128, K = 256
__global__ __launch_bounds__(256) void sage_gemm(
    const unsigned short* __restrict__ Fm,    // [NPAD,128] bf16 (mean)
    const unsigned short* __restrict__ Self,  // [NPAD,128] bf16 (self feats)
    const unsigned short* __restrict__ Wc,    // [128,256] bf16
    const float* __restrict__ bias,           // [128]
    void* __restrict__ outv, int relu, int obf16) {
    __shared__ unsigned short wl[128 * 264];  // pitch 264 shorts (bank shift 4)
    for (int cidx = threadIdx.x; cidx < 4096; cidx += 256) {
        int row = cidx >> 5, chunk = cidx & 31;
        const uint4 v = *(const uint4*)(Wc + row * 256 + chunk * 8);
        *(uint4*)(&wl[row * 264 + chunk * 8]) = v;
    }
    __syncthreads();

    const int wave = threadIdx.x >> 6;
    const int lane = threadIdx.x & 63;
    const int m = lane & 15;
    const int q = lane >> 4;
    const int tile0 = blockIdx.x * 8 + wave * 2;

    const size_t rowoff = (size_t)(tile0 * 16 + m) * C + q * 8;
    const unsigned short* am = Fm + rowoff;
    const unsigned short* as = Self + rowoff;

    f32x4 acc[2][8];
#pragma unroll
    for (int t = 0; t < 2; ++t)
#pragma unroll
        for (int j = 0; j < 8; ++j) acc[t][j] = (f32x4){0.f, 0.f, 0.f, 0.f};

#pragma unroll
    for (int kt = 0; kt < 8; ++kt) {
        const unsigned short* A = (kt < 4) ? am : as;
        const int ko = (kt & 3) * 32;
        bf16x8 af0 = *(const bf16x8*)(A + ko);
        bf16x8 af1 = *(const bf16x8*)(A + 16 * C + ko);
#pragma unroll
        for (int jt = 0; jt < 8; ++jt) {
            bf16x8 bfrag = *(const bf16x8*)(&wl[(jt * 16 + m) * 264 + kt * 32 + q * 8]);
            acc[0][jt] = __builtin_amdgcn_mfma_f32_16x16x32_bf16(af0, bfrag, acc[0][jt], 0, 0, 0);
            acc[1][jt] = __builtin_amdgcn_mfma_f32_16x16x32_bf16(af1, bfrag, acc[1][jt], 0, 0, 0);
        }
    }

#pragma unroll
    for (int t = 0; t < 2; ++t) {
        int rbase = (tile0 + t) * 16 + q * 4;
#pragma unroll
        for (int r = 0; r < 4; ++r) {
            int row = rbase + r;
            if (row < N_NODES) {
#pragma unroll
                for (int jt = 0; jt < 8; ++jt) {
                    int col = jt * 16 + m;
                    float v = acc[t][jt][r] + bias[col];
                    if (relu) v = fmaxf(v, 0.0f);
                    if (obf16)
                        ((unsigned short*)outv)[(size_t)row * C + col] = f2bf(v);
                    else
                        ((float*)outv)[(size_t)row * C + col] = v;
                }
            }
        }
    }
}

extern "C" void kernel_launch(void* const* d_in, const int* in_sizes, int n_in,
                              void* d_out, int out_size, void* d_ws, size_t ws_size,
                              hipStream_t stream) {
    const float* x = (const float*)d_in[0];
    const int* edge = (const int*)d_in[1];   // int64 in reference -> int32 in harness
    const float* Wl1 = (const float*)d_in[2];
    const float* bl1 = (const float*)d_in[3];
    const float* Wr1 = (const float*)d_in[4];
    const float* Wl2 = (const float*)d_in[5];
    const float* bl2 = (const float*)d_in[6];
    const float* Wr2 = (const float*)d_in[7];
    float* out = (float*)d_out;

    const int E = in_sizes[1] / 2;
    const int* src = edge;
    const int* dst = edge + E;

    // workspace layout
    char* ws = (char*)d_ws;
    size_t off = 0;
    int* deg = (int*)(ws + off);              off += ((size_t)N_NODES * 4 + 511) & ~511ull;
    int* row_ptr = (int*)(ws + off);          off += ((size_t)NPAD * 4 + 511) & ~511ull;
    int* scanbuf = (int*)(ws + off);          off += ((size_t)NPAD * 4 + 511) & ~511ull;
    int* blocksum = (int*)(ws + off);         off += 512 * 4;
    int* blockoff = (int*)(ws + off);         off += 512 * 4;
    int* cursor = (int*)(ws + off);           off += ((size_t)N_NODES * 4 + 511) & ~511ull;
    int* csr_src = (int*)(ws + off);          off += ((size_t)E * 4 + 511) & ~511ull;
    unsigned short* Xb = (unsigned short*)(ws + off); off += (size_t)NPAD * C * 2;  // 12.8 MB
    unsigned short* Fm = (unsigned short*)(ws + off); off += (size_t)NPAD * C * 2;  // 12.8 MB
    unsigned short* h  = (unsigned short*)(ws + off); off += (size_t)NPAD * C * 2;  // 12.8 MB
    unsigned short* Wc1 = (unsigned short*)(ws + off); off += 128 * 256 * 2;
    unsigned short* Wc2 = (unsigned short*)(ws + off); off += 128 * 256 * 2;
    (void)ws_size;

    const int edgeBlocks = (E + 255) / 256;
    const int gatherBlocks = (NPAD * 64) / 256;   // one wave per node
    const int xprepBlocks = (N_NODES * C / 8 + 255) / 256;

    // CSR build + weight/feature conversion (once)
    hipMemsetAsync(deg, 0, (size_t)N_NODES * 4, stream);
    hipMemsetAsync(cursor, 0, (size_t)N_NODES * 4, stream);
    deg_kernel<<<edgeBlocks, 256, 0, stream>>>(dst, deg, E);
    scan1_kernel<<<SCAN1_BLOCKS, 256, 0, stream>>>(deg, scanbuf, blocksum);
    scan2_kernel<<<1, 256, 0, stream>>>(blocksum, blockoff);
    scan3_kernel<<<SCAN1_BLOCKS, 256, 0, stream>>>(scanbuf, blockoff, row_ptr);
    fill_kernel<<<edgeBlocks, 256, 0, stream>>>(src, dst, row_ptr, cursor, csr_src, E);
    xprep_kernel<<<xprepBlocks, 256, 0, stream>>>(x, Xb);
    wprep_kernel<<<256, 256, 0, stream>>>(Wl1, Wr1, Wl2, Wr2, Wc1, Wc2);

    // layer 1
    gather_kernel<<<gatherBlocks, 256, 0, stream>>>(Xb, row_ptr, csr_src, Fm);
    sage_gemm<<<GEMM_BLOCKS, 256, 0, stream>>>(Fm, Xb, Wc1, bl1, h, 1, 1);

    // layer 2
    gather_kernel<<<gatherBlocks, 256, 0, stream>>>(h, row_ptr, csr_src, Fm);
    sage_gemm<<<GEMM_BLOCKS, 256, 0, stream>>>(Fm, h, Wc2, bl2, out, 0, 0);
}

// Round 6
// 256.971 us; speedup vs baseline: 8.5597x; 1.0992x over previous
//
#include <hip/hip_runtime.h>
#include <hip/hip_bf16.h>

#define N_NODES 50000
#define C 128
#define NPAD 50176            // 3136 row-tiles of 16; 392 blocks * 8 tiles
#define NTILES (NPAD / 16)
#define GEMM_BLOCKS (NTILES / 8)  // 392
#define SCAN1_BLOCKS (NPAD / 256) // 196
#define XPREP_BLOCKS 3125         // 800000 / 256
#define WPREP_BLOCKS 256

typedef short bf16x8 __attribute__((ext_vector_type(8)));
typedef float f32x4 __attribute__((ext_vector_type(4)));

__device__ __forceinline__ unsigned short f2bf(float f) {
    unsigned int u = __float_as_uint(f);
    unsigned int r = u + 0x7fffu + ((u >> 16) & 1u);
    return (unsigned short)(r >> 16);
}

__device__ __forceinline__ float bf2f(unsigned short b) {
    return __uint_as_float(((unsigned int)b) << 16);
}

// ---- degree histogram (int), once
__global__ void deg_kernel(const int* __restrict__ dst, int* __restrict__ deg, int E) {
    int e = blockIdx.x * 256 + threadIdx.x;
    if (e < E) {
        int d = dst[e];
        if ((unsigned)d < (unsigned)N_NODES) atomicAdd(deg + d, 1);
    }
}

// ---- hierarchical exclusive scan, phases 1-2 (phase 3 folded into consumers)
__global__ __launch_bounds__(256) void scan1_kernel(const int* __restrict__ deg,
                                                    int* __restrict__ scanbuf,
                                                    int* __restrict__ blocksum) {
    int i = blockIdx.x * 256 + threadIdx.x;
    int v = (i < N_NODES) ? deg[i] : 0;
    int lane = threadIdx.x & 63;
    int wv = threadIdx.x >> 6;
    int s = v;
#pragma unroll
    for (int off = 1; off < 64; off <<= 1) {
        int t = __shfl_up(s, off, 64);
        if (lane >= off) s += t;
    }
    __shared__ int wsum[4];
    if (lane == 63) wsum[wv] = s;
    __syncthreads();
    int woff = 0;
#pragma unroll
    for (int k = 0; k < 4; ++k) woff += (k < wv) ? wsum[k] : 0;
    scanbuf[i] = s + woff - v;                       // block-local exclusive
    if (threadIdx.x == 255) blocksum[blockIdx.x] = s + woff;  // block total
}

__global__ __launch_bounds__(256) void scan2_kernel(const int* __restrict__ blocksum,
                                                    int* __restrict__ blockoff) {
    int t = threadIdx.x;
    int v = (t < SCAN1_BLOCKS) ? blocksum[t] : 0;
    int lane = t & 63, wv = t >> 6;
    int s = v;
#pragma unroll
    for (int off = 1; off < 64; off <<= 1) {
        int tmp = __shfl_up(s, off, 64);
        if (lane >= off) s += tmp;
    }
    __shared__ int wsum[4];
    if (lane == 63) wsum[wv] = s;
    __syncthreads();
    int woff = 0;
#pragma unroll
    for (int k = 0; k < 4; ++k) woff += (k < wv) ? wsum[k] : 0;
    if (t < SCAN1_BLOCKS) blockoff[t] = s + woff - v;   // exclusive block offsets
}

// row_ptr(i) = scanbuf[i] + blockoff[i>>8], computed inline by consumers

// ---- fill CSR (row_ptr on the fly)
__global__ void fill_kernel(const int* __restrict__ src, const int* __restrict__ dst,
                            const int* __restrict__ scanbuf, const int* __restrict__ blockoff,
                            int* __restrict__ cursor, int* __restrict__ csr_src, int E) {
    int e = blockIdx.x * 256 + threadIdx.x;
    if (e < E) {
        int d = dst[e];
        int s = src[e];
        if ((unsigned)d < (unsigned)N_NODES && (unsigned)s < (unsigned)N_NODES) {
            int rp = scanbuf[d] + blockoff[d >> 8];
            int pos = rp + atomicAdd(cursor + d, 1);
            csr_src[pos] = s;
        }
    }
}

// ---- gather mean from bf16 features: one wave per node, 2 bf16 per lane, unroll x4
__global__ __launch_bounds__(256) void gather_kernel(
    const unsigned short* __restrict__ feat,  // [*, 128] bf16
    const int* __restrict__ scanbuf, const int* __restrict__ blockoff,
    const int* __restrict__ csr_src, unsigned short* __restrict__ Fm) {
    int w = (blockIdx.x * 256 + threadIdx.x) >> 6;   // node id (one wave each)
    int lane = threadIdx.x & 63;
    if (w >= N_NODES) return;
    const int beg = scanbuf[w] + blockoff[w >> 8];
    const int end = scanbuf[w + 1] + blockoff[(w + 1) >> 8];
    float ax = 0.f, ay = 0.f;
    const unsigned short* fp = feat + lane * 2;
    int i = beg;
    for (; i + 3 < end; i += 4) {
        int s0 = csr_src[i];
        int s1 = csr_src[i + 1];
        int s2 = csr_src[i + 2];
        int s3 = csr_src[i + 3];
        unsigned int u0 = *(const unsigned int*)(fp + (size_t)s0 * C);
        unsigned int u1 = *(const unsigned int*)(fp + (size_t)s1 * C);
        unsigned int u2 = *(const unsigned int*)(fp + (size_t)s2 * C);
        unsigned int u3 = *(const unsigned int*)(fp + (size_t)s3 * C);
        ax += bf2f((unsigned short)u0) + bf2f((unsigned short)u1) +
              bf2f((unsigned short)u2) + bf2f((unsigned short)u3);
        ay += bf2f((unsigned short)(u0 >> 16)) + bf2f((unsigned short)(u1 >> 16)) +
              bf2f((unsigned short)(u2 >> 16)) + bf2f((unsigned short)(u3 >> 16));
    }
    for (; i < end; ++i) {
        int s0 = csr_src[i];
        unsigned int u0 = *(const unsigned int*)(fp + (size_t)s0 * C);
        ax += bf2f((unsigned short)u0);
        ay += bf2f((unsigned short)(u0 >> 16));
    }
    const float inv = 1.0f / fmaxf((float)(end - beg), 1.0f);
    unsigned int mpack = (unsigned)f2bf(ax * inv) | ((unsigned)f2bf(ay * inv) << 16);
    *(unsigned int*)(Fm + (size_t)w * C + lane * 2) = mpack;
}

// ---- fused feature-cast + weight prep (one launch)
__global__ __launch_bounds__(256) void xwprep_kernel(
    const float* __restrict__ x, unsigned short* __restrict__ Xb,
    const float* __restrict__ Wl1, const float* __restrict__ Wr1,
    const float* __restrict__ Wl2, const float* __restrict__ Wr2,
    unsigned short* __restrict__ Wc1, unsigned short* __restrict__ Wc2) {
    int b = blockIdx.x;
    if (b < XPREP_BLOCKS) {
        int t = b * 256 + threadIdx.x;
        if (t >= N_NODES * C / 8) return;
        const float4 a = *(const float4*)(x + (size_t)t * 8);
        const float4 c = *(const float4*)(x + (size_t)t * 8 + 4);
        unsigned short o[8] = {f2bf(a.x), f2bf(a.y), f2bf(a.z), f2bf(a.w),
                               f2bf(c.x), f2bf(c.y), f2bf(c.z), f2bf(c.w)};
        *(uint4*)(Xb + (size_t)t * 8) = *(const uint4*)o;
    } else {
        int idx = (b - XPREP_BLOCKS) * 256 + threadIdx.x;  // 2*128*256 = 65536
        int layer = idx >> 15;
        int r = idx & 32767;
        int j = r >> 8, k = r & 255;
        const float* Wl = layer ? Wl2 : Wl1;
        const float* Wr = layer ? Wr2 : Wr1;
        unsigned short* Wc = layer ? Wc2 : Wc1;
        float f = (k < 128) ? Wl[j * 128 + k] : Wr[j * 128 + (k - 128)];
        Wc[r] = f2bf(f);
    }
}

// ---- GEMM: out[n][j] = sum_k A[n][k]*Wc[j][k] + bias[j]
// A = [Fm | Self] (two [*,128] bf16 matrices), M = NPAD, N = 128, K = 256
__global__ __launch_bounds__(256) void sage_gemm(
    const unsigned short* __restrict__ Fm,    // [NPAD,128] bf16 (mean)
    const unsigned short* __restrict__ Self,  // [NPAD,128] bf16 (self feats)
    const unsigned short* __restrict__ Wc,    // [128,256] bf16
    const float* __restrict__ bias,           // [128]
    void* __restrict__ outv, int relu, int obf16) {
    __shared__ unsigned short wl[128 * 264];  // pitch 264 shorts (bank shift 4)
    for (int cidx = threadIdx.x; cidx < 4096; cidx += 256) {
        int row = cidx >> 5, chunk = cidx & 31;
        const uint4 v = *(const uint4*)(Wc + row * 256 + chunk * 8);
        *(uint4*)(&wl[row * 264 + chunk * 8]) = v;
    }
    __syncthreads();

    const int wave = threadIdx.x >> 6;
    const int lane = threadIdx.x & 63;
    const int m = lane & 15;
    const int q = lane >> 4;
    const int tile0 = blockIdx.x * 8 + wave * 2;

    const size_t rowoff = (size_t)(tile0 * 16 + m) * C + q * 8;
    const unsigned short* am = Fm + rowoff;
    const unsigned short* as = Self + rowoff;

    f32x4 acc[2][8];
#pragma unroll
    for (int t = 0; t < 2; ++t)
#pragma unroll
        for (int j = 0; j < 8; ++j) acc[t][j] = (f32x4){0.f, 0.f, 0.f, 0.f};

#pragma unroll
    for (int kt = 0; kt < 8; ++kt) {
        const unsigned short* A = (kt < 4) ? am : as;
        const int ko = (kt & 3) * 32;
        bf16x8 af0 = *(const bf16x8*)(A + ko);
        bf16x8 af1 = *(const bf16x8*)(A + 16 * C + ko);
#pragma unroll
        for (int jt = 0; jt < 8; ++jt) {
            bf16x8 bfrag = *(const bf16x8*)(&wl[(jt * 16 + m) * 264 + kt * 32 + q * 8]);
            acc[0][jt] = __builtin_amdgcn_mfma_f32_16x16x32_bf16(af0, bfrag, acc[0][jt], 0, 0, 0);
            acc[1][jt] = __builtin_amdgcn_mfma_f32_16x16x32_bf16(af1, bfrag, acc[1][jt], 0, 0, 0);
        }
    }

#pragma unroll
    for (int t = 0; t < 2; ++t) {
        int rbase = (tile0 + t) * 16 + q * 4;
#pragma unroll
        for (int r = 0; r < 4; ++r) {
            int row = rbase + r;
            if (row < N_NODES) {
#pragma unroll
                for (int jt = 0; jt < 8; ++jt) {
                    int col = jt * 16 + m;
                    float v = acc[t][jt][r] + bias[col];
                    if (relu) v = fmaxf(v, 0.0f);
                    if (obf16)
                        ((unsigned short*)outv)[(size_t)row * C + col] = f2bf(v);
                    else
                        ((float*)outv)[(size_t)row * C + col] = v;
                }
            }
        }
    }
}

extern "C" void kernel_launch(void* const* d_in, const int* in_sizes, int n_in,
                              void* d_out, int out_size, void* d_ws, size_t ws_size,
                              hipStream_t stream) {
    const float* x = (const float*)d_in[0];
    const int* edge = (const int*)d_in[1];   // int64 in reference -> int32 in harness
    const float* Wl1 = (const float*)d_in[2];
    const float* bl1 = (const float*)d_in[3];
    const float* Wr1 = (const float*)d_in[4];
    const float* Wl2 = (const float*)d_in[5];
    const float* bl2 = (const float*)d_in[6];
    const float* Wr2 = (const float*)d_in[7];
    float* out = (float*)d_out;

    const int E = in_sizes[1] / 2;
    const int* src = edge;
    const int* dst = edge + E;

    // workspace layout (deg and cursor contiguous -> one memset)
    char* ws = (char*)d_ws;
    size_t off = 0;
    int* deg = (int*)(ws + off);              off += (size_t)N_NODES * 4;            // 200 KB
    int* cursor = (int*)(ws + off);           off += (size_t)N_NODES * 4;            // 200 KB
    off = (off + 511) & ~511ull;
    int* scanbuf = (int*)(ws + off);          off += ((size_t)NPAD * 4 + 511) & ~511ull;
    int* blocksum = (int*)(ws + off);         off += 512 * 4;
    int* blockoff = (int*)(ws + off);         off += 512 * 4;
    int* csr_src = (int*)(ws + off);          off += ((size_t)E * 4 + 511) & ~511ull;
    unsigned short* Xb = (unsigned short*)(ws + off); off += (size_t)NPAD * C * 2;  // 12.8 MB
    unsigned short* Fm = (unsigned short*)(ws + off); off += (size_t)NPAD * C * 2;  // 12.8 MB
    unsigned short* h  = (unsigned short*)(ws + off); off += (size_t)NPAD * C * 2;  // 12.8 MB
    unsigned short* Wc1 = (unsigned short*)(ws + off); off += 128 * 256 * 2;
    unsigned short* Wc2 = (unsigned short*)(ws + off); off += 128 * 256 * 2;
    (void)ws_size;

    const int edgeBlocks = (E + 255) / 256;
    const int gatherBlocks = (NPAD * 64) / 256;   // one wave per node

    // CSR build + feature/weight conversion
    hipMemsetAsync(deg, 0, (size_t)N_NODES * 8, stream);  // deg + cursor
    deg_kernel<<<edgeBlocks, 256, 0, stream>>>(dst, deg, E);
    scan1_kernel<<<SCAN1_BLOCKS, 256, 0, stream>>>(deg, scanbuf, blocksum);
    scan2_kernel<<<1, 256, 0, stream>>>(blocksum, blockoff);
    fill_kernel<<<edgeBlocks, 256, 0, stream>>>(src, dst, scanbuf, blockoff, cursor, csr_src, E);
    xwprep_kernel<<<XPREP_BLOCKS + WPREP_BLOCKS, 256, 0, stream>>>(
        x, Xb, Wl1, Wr1, Wl2, Wr2, Wc1, Wc2);

    // layer 1
    gather_kernel<<<gatherBlocks, 256, 0, stream>>>(Xb, scanbuf, blockoff, csr_src, Fm);
    sage_gemm<<<GEMM_BLOCKS, 256, 0, stream>>>(Fm, Xb, Wc1, bl1, h, 1, 1);

    // layer 2
    gather_kernel<<<gatherBlocks, 256, 0, stream>>>(h, scanbuf, blockoff, csr_src, Fm);
    sage_gemm<<<GEMM_BLOCKS, 256, 0, stream>>>(Fm, h, Wc2, bl2, out, 0, 0);
}

// Round 7
// 244.279 us; speedup vs baseline: 9.0044x; 1.0520x over previous
//
#include <hip/hip_runtime.h>
#include <hip/hip_bf16.h>

#define N_NODES 50000
#define C 128
#define NPAD 50176            // 3136 row-tiles of 16; 392 blocks * 8 tiles
#define NTILES (NPAD / 16)
#define GEMM_BLOCKS (NTILES / 8)  // 392
#define SCAN1_BLOCKS (NPAD / 256) // 196
#define XPREP_BLOCKS 3125         // 800000 / 256
#define WPREP_BLOCKS 256

typedef short bf16x8 __attribute__((ext_vector_type(8)));
typedef float f32x4 __attribute__((ext_vector_type(4)));

__device__ __forceinline__ unsigned short f2bf(float f) {
    unsigned int u = __float_as_uint(f);
    unsigned int r = u + 0x7fffu + ((u >> 16) & 1u);
    return (unsigned short)(r >> 16);
}

__device__ __forceinline__ float bf2f(unsigned short b) {
    return __uint_as_float(((unsigned int)b) << 16);
}

// ---- fused: degree histogram + x->bf16 cast + weight cast (block-range split)
__global__ __launch_bounds__(256) void build_kernel(
    const int* __restrict__ dst, int* __restrict__ deg, int E, int edgeBlocks,
    const float* __restrict__ x, unsigned short* __restrict__ Xb,
    const float* __restrict__ Wl1, const float* __restrict__ Wr1,
    const float* __restrict__ Wl2, const float* __restrict__ Wr2,
    unsigned short* __restrict__ Wc1, unsigned short* __restrict__ Wc2) {
    int b = blockIdx.x;
    if (b < edgeBlocks) {
        int e = b * 256 + threadIdx.x;
        if (e < E) {
            int d = dst[e];
            if ((unsigned)d < (unsigned)N_NODES) atomicAdd(deg + d, 1);
        }
    } else if (b < edgeBlocks + XPREP_BLOCKS) {
        int t = (b - edgeBlocks) * 256 + threadIdx.x;
        if (t >= N_NODES * C / 8) return;
        const float4 a = *(const float4*)(x + (size_t)t * 8);
        const float4 c = *(const float4*)(x + (size_t)t * 8 + 4);
        unsigned short o[8] = {f2bf(a.x), f2bf(a.y), f2bf(a.z), f2bf(a.w),
                               f2bf(c.x), f2bf(c.y), f2bf(c.z), f2bf(c.w)};
        *(uint4*)(Xb + (size_t)t * 8) = *(const uint4*)o;
    } else {
        int idx = (b - edgeBlocks - XPREP_BLOCKS) * 256 + threadIdx.x;  // 65536
        int layer = idx >> 15;
        int r = idx & 32767;
        int j = r >> 8, k = r & 255;
        const float* Wl = layer ? Wl2 : Wl1;
        const float* Wr = layer ? Wr2 : Wr1;
        unsigned short* Wc = layer ? Wc2 : Wc1;
        float f = (k < 128) ? Wl[j * 128 + k] : Wr[j * 128 + (k - 128)];
        Wc[r] = f2bf(f);
    }
}

// ---- hierarchical exclusive scan, phases 1-2 (phase 3 folded into consumers)
__global__ __launch_bounds__(256) void scan1_kernel(const int* __restrict__ deg,
                                                    int* __restrict__ scanbuf,
                                                    int* __restrict__ blocksum) {
    int i = blockIdx.x * 256 + threadIdx.x;
    int v = (i < N_NODES) ? deg[i] : 0;
    int lane = threadIdx.x & 63;
    int wv = threadIdx.x >> 6;
    int s = v;
#pragma unroll
    for (int off = 1; off < 64; off <<= 1) {
        int t = __shfl_up(s, off, 64);
        if (lane >= off) s += t;
    }
    __shared__ int wsum[4];
    if (lane == 63) wsum[wv] = s;
    __syncthreads();
    int woff = 0;
#pragma unroll
    for (int k = 0; k < 4; ++k) woff += (k < wv) ? wsum[k] : 0;
    scanbuf[i] = s + woff - v;                       // block-local exclusive
    if (threadIdx.x == 255) blocksum[blockIdx.x] = s + woff;  // block total
}

__global__ __launch_bounds__(256) void scan2_kernel(const int* __restrict__ blocksum,
                                                    int* __restrict__ blockoff) {
    int t = threadIdx.x;
    int v = (t < SCAN1_BLOCKS) ? blocksum[t] : 0;
    int lane = t & 63, wv = t >> 6;
    int s = v;
#pragma unroll
    for (int off = 1; off < 64; off <<= 1) {
        int tmp = __shfl_up(s, off, 64);
        if (lane >= off) s += tmp;
    }
    __shared__ int wsum[4];
    if (lane == 63) wsum[wv] = s;
    __syncthreads();
    int woff = 0;
#pragma unroll
    for (int k = 0; k < 4; ++k) woff += (k < wv) ? wsum[k] : 0;
    if (t < SCAN1_BLOCKS) blockoff[t] = s + woff - v;   // exclusive block offsets
}

// row_ptr(i) = scanbuf[i] + blockoff[i>>8], computed inline by consumers

// ---- fill CSR (row_ptr on the fly)
__global__ void fill_kernel(const int* __restrict__ src, const int* __restrict__ dst,
                            const int* __restrict__ scanbuf, const int* __restrict__ blockoff,
                            int* __restrict__ cursor, int* __restrict__ csr_src, int E) {
    int e = blockIdx.x * 256 + threadIdx.x;
    if (e < E) {
        int d = dst[e];
        int s = src[e];
        if ((unsigned)d < (unsigned)N_NODES && (unsigned)s < (unsigned)N_NODES) {
            int rp = scanbuf[d] + blockoff[d >> 8];
            int pos = rp + atomicAdd(cursor + d, 1);
            csr_src[pos] = s;
        }
    }
}

// ---- gather mean: one wave per node; indices prefetched lane-parallel then
//      broadcast via __shfl so all row-loads are independent (MLP >> 1)
__global__ __launch_bounds__(256) void gather_kernel(
    const unsigned short* __restrict__ feat,  // [*, 128] bf16
    const int* __restrict__ scanbuf, const int* __restrict__ blockoff,
    const int* __restrict__ csr_src, unsigned short* __restrict__ Fm) {
    int w = (blockIdx.x * 256 + threadIdx.x) >> 6;   // node id (one wave each)
    int lane = threadIdx.x & 63;
    if (w >= N_NODES) return;
    const int beg = scanbuf[w] + blockoff[w >> 8];
    const int end = scanbuf[w + 1] + blockoff[(w + 1) >> 8];
    const int deg = end - beg;
    float ax = 0.f, ay = 0.f;
    const unsigned short* fp = feat + lane * 2;
    for (int base = beg; base < end; base += 64) {
        const int cnt = min(64, end - base);
        int myidx = 0;
        if (lane < cnt) myidx = csr_src[base + lane];  // one coalesced index load
        int j = 0;
        for (; j + 3 < cnt; j += 4) {
            int s0 = __shfl(myidx, j);
            int s1 = __shfl(myidx, j + 1);
            int s2 = __shfl(myidx, j + 2);
            int s3 = __shfl(myidx, j + 3);
            unsigned int u0 = *(const unsigned int*)(fp + (size_t)s0 * C);
            unsigned int u1 = *(const unsigned int*)(fp + (size_t)s1 * C);
            unsigned int u2 = *(const unsigned int*)(fp + (size_t)s2 * C);
            unsigned int u3 = *(const unsigned int*)(fp + (size_t)s3 * C);
            ax += bf2f((unsigned short)u0) + bf2f((unsigned short)u1) +
                  bf2f((unsigned short)u2) + bf2f((unsigned short)u3);
            ay += bf2f((unsigned short)(u0 >> 16)) + bf2f((unsigned short)(u1 >> 16)) +
                  bf2f((unsigned short)(u2 >> 16)) + bf2f((unsigned short)(u3 >> 16));
        }
        for (; j < cnt; ++j) {
            int s0 = __shfl(myidx, j);
            unsigned int u0 = *(const unsigned int*)(fp + (size_t)s0 * C);
            ax += bf2f((unsigned short)u0);
            ay += bf2f((unsigned short)(u0 >> 16));
        }
    }
    const float inv = 1.0f / fmaxf((float)deg, 1.0f);
    unsigned int mpack = (unsigned)f2bf(ax * inv) | ((unsigned)f2bf(ay * inv) << 16);
    *(unsigned int*)(Fm + (size_t)w * C + lane * 2) = mpack;
}

// ---- GEMM: out[n][j] = sum_k A[n][k]*Wc[j][k] + bias[j]
// A = [Fm | Self] (two [*,128] bf16 matrices), M = NPAD, N = 128, K = 256
__global__ __launch_bounds__(256) void sage_gemm(
    const unsigned short* __restrict__ Fm,    // [NPAD,128] bf16 (mean)
    const unsigned short* __restrict__ Self,  // [NPAD,128] bf16 (self feats)
    const unsigned short* __restrict__ Wc,    // [128,256] bf16
    const float* __restrict__ bias,           // [128]
    void* __restrict__ outv, int relu, int obf16) {
    __shared__ unsigned short wl[128 * 264];  // pitch 264 shorts (bank shift 4)
    for (int cidx = threadIdx.x; cidx < 4096; cidx += 256) {
        int row = cidx >> 5, chunk = cidx & 31;
        const uint4 v = *(const uint4*)(Wc + row * 256 + chunk * 8);
        *(uint4*)(&wl[row * 264 + chunk * 8]) = v;
    }
    __syncthreads();

    const int wave = threadIdx.x >> 6;
    const int lane = threadIdx.x & 63;
    const int m = lane & 15;
    const int q = lane >> 4;
    const int tile0 = blockIdx.x * 8 + wave * 2;

    const size_t rowoff = (size_t)(tile0 * 16 + m) * C + q * 8;
    const unsigned short* am = Fm + rowoff;
    const unsigned short* as = Self + rowoff;

    f32x4 acc[2][8];
#pragma unroll
    for (int t = 0; t < 2; ++t)
#pragma unroll
        for (int j = 0; j < 8; ++j) acc[t][j] = (f32x4){0.f, 0.f, 0.f, 0.f};

#pragma unroll
    for (int kt = 0; kt < 8; ++kt) {
        const unsigned short* A = (kt < 4) ? am : as;
        const int ko = (kt & 3) * 32;
        bf16x8 af0 = *(const bf16x8*)(A + ko);
        bf16x8 af1 = *(const bf16x8*)(A + 16 * C + ko);
#pragma unroll
        for (int jt = 0; jt < 8; ++jt) {
            bf16x8 bfrag = *(const bf16x8*)(&wl[(jt * 16 + m) * 264 + kt * 32 + q * 8]);
            acc[0][jt] = __builtin_amdgcn_mfma_f32_16x16x32_bf16(af0, bfrag, acc[0][jt], 0, 0, 0);
            acc[1][jt] = __builtin_amdgcn_mfma_f32_16x16x32_bf16(af1, bfrag, acc[1][jt], 0, 0, 0);
        }
    }

#pragma unroll
    for (int t = 0; t < 2; ++t) {
        int rbase = (tile0 + t) * 16 + q * 4;
#pragma unroll
        for (int r = 0; r < 4; ++r) {
            int row = rbase + r;
            if (row < N_NODES) {
#pragma unroll
                for (int jt = 0; jt < 8; ++jt) {
                    int col = jt * 16 + m;
                    float v = acc[t][jt][r] + bias[col];
                    if (relu) v = fmaxf(v, 0.0f);
                    if (obf16)
                        ((unsigned short*)outv)[(size_t)row * C + col] = f2bf(v);
                    else
                        ((float*)outv)[(size_t)row * C + col] = v;
                }
            }
        }
    }
}

extern "C" void kernel_launch(void* const* d_in, const int* in_sizes, int n_in,
                              void* d_out, int out_size, void* d_ws, size_t ws_size,
                              hipStream_t stream) {
    const float* x = (const float*)d_in[0];
    const int* edge = (const int*)d_in[1];   // int64 in reference -> int32 in harness
    const float* Wl1 = (const float*)d_in[2];
    const float* bl1 = (const float*)d_in[3];
    const float* Wr1 = (const float*)d_in[4];
    const float* Wl2 = (const float*)d_in[5];
    const float* bl2 = (const float*)d_in[6];
    const float* Wr2 = (const float*)d_in[7];
    float* out = (float*)d_out;

    const int E = in_sizes[1] / 2;
    const int* src = edge;
    const int* dst = edge + E;

    // workspace layout (deg and cursor contiguous -> one memset)
    char* ws = (char*)d_ws;
    size_t off = 0;
    int* deg = (int*)(ws + off);              off += (size_t)N_NODES * 4;            // 200 KB
    int* cursor = (int*)(ws + off);           off += (size_t)N_NODES * 4;            // 200 KB
    off = (off + 511) & ~511ull;
    int* scanbuf = (int*)(ws + off);          off += ((size_t)NPAD * 4 + 511) & ~511ull;
    int* blocksum = (int*)(ws + off);         off += 512 * 4;
    int* blockoff = (int*)(ws + off);         off += 512 * 4;
    int* csr_src = (int*)(ws + off);          off += ((size_t)E * 4 + 511) & ~511ull;
    unsigned short* Xb = (unsigned short*)(ws + off); off += (size_t)NPAD * C * 2;  // 12.8 MB
    unsigned short* Fm = (unsigned short*)(ws + off); off += (size_t)NPAD * C * 2;  // 12.8 MB
    unsigned short* h  = (unsigned short*)(ws + off); off += (size_t)NPAD * C * 2;  // 12.8 MB
    unsigned short* Wc1 = (unsigned short*)(ws + off); off += 128 * 256 * 2;
    unsigned short* Wc2 = (unsigned short*)(ws + off); off += 128 * 256 * 2;
    (void)ws_size;

    const int edgeBlocks = (E + 255) / 256;
    const int gatherBlocks = (NPAD * 64) / 256;   // one wave per node

    // CSR build + feature/weight conversion
    hipMemsetAsync(deg, 0, (size_t)N_NODES * 8, stream);  // deg + cursor
    build_kernel<<<edgeBlocks + XPREP_BLOCKS + WPREP_BLOCKS, 256, 0, stream>>>(
        dst, deg, E, edgeBlocks, x, Xb, Wl1, Wr1, Wl2, Wr2, Wc1, Wc2);
    scan1_kernel<<<SCAN1_BLOCKS, 256, 0, stream>>>(deg, scanbuf, blocksum);
    scan2_kernel<<<1, 256, 0, stream>>>(blocksum, blockoff);
    fill_kernel<<<edgeBlocks, 256, 0, stream>>>(src, dst, scanbuf, blockoff, cursor, csr_src, E);

    // layer 1
    gather_kernel<<<gatherBlocks, 256, 0, stream>>>(Xb, scanbuf, blockoff, csr_src, Fm);
    sage_gemm<<<GEMM_BLOCKS, 256, 0, stream>>>(Fm, Xb, Wc1, bl1, h, 1, 1);

    // layer 2
    gather_kernel<<<gatherBlocks, 256, 0, stream>>>(h, scanbuf, blockoff, csr_src, Fm);
    sage_gemm<<<GEMM_BLOCKS, 256, 0, stream>>>(Fm, h, Wc2, bl2, out, 0, 0);
}